// Round 13
// baseline (215.035 us; speedup 1.0000x reference)
//
#include <hip/hip_runtime.h>

#define NN 8192
#define CC 512

typedef __attribute__((ext_vector_type(8))) short short8;
typedef __attribute__((ext_vector_type(4))) float f32x4;
typedef unsigned short ushort_t;

__device__ __forceinline__ unsigned short f2bf(float f) {
    unsigned int u = __float_as_uint(f);
    u += 0x7FFF + ((u >> 16) & 1);
    return (unsigned short)(u >> 16);
}
__device__ __forceinline__ float bf2f(unsigned short u) {
    return __uint_as_float(((unsigned int)u) << 16);
}

__device__ __forceinline__ void gload_lds16(const void* g, void* l) {
    __builtin_amdgcn_global_load_lds((const __attribute__((address_space(1))) unsigned int*)g,
                                     (__attribute__((address_space(3))) unsigned int*)l,
                                     16, 0, 0);
}

// ---------------- fused pre-kernel: blocks 0..255 -> z = x@w ; blocks 256..8447 -> rowsum+cvt ----------------
__global__ __launch_bounds__(256) void k_pre(const float* __restrict__ x,
                                             const float* __restrict__ adj,
                                             const ushort_t* __restrict__ wt,
                                             float* __restrict__ ds,
                                             ushort_t* __restrict__ adj16,
                                             float* __restrict__ z) {
    __shared__ __align__(16) ushort_t As[128 * 64];
    __shared__ __align__(16) ushort_t Bs[128 * 64];
    __shared__ float partial[4];

    int t = threadIdx.x;
    if (blockIdx.x >= 256) {
        // ---------- rowsum + bf16 convert ----------
        int row = blockIdx.x - 256;
        const float4* p = (const float4*)(adj + (size_t)row * NN);
        ushort4* q = (ushort4*)(adj16 + (size_t)row * NN);
        float s = 0.f;
#pragma unroll
        for (int i = 0; i < 8; ++i) {
            float4 v = p[t + i * 256];
            s += (v.x + v.y) + (v.z + v.w);
            ushort4 u;
            u.x = f2bf(v.x); u.y = f2bf(v.y); u.z = f2bf(v.z); u.w = f2bf(v.w);
            q[t + i * 256] = u;
        }
#pragma unroll
        for (int off = 32; off > 0; off >>= 1) s += __shfl_down(s, off, 64);
        if ((t & 63) == 0) partial[t >> 6] = s;
        __syncthreads();
        if (t == 0) {
            float deg = ((partial[0] + partial[1]) + (partial[2] + partial[3])) + 1.0f;
            ds[row] = rsqrtf(deg);
        }
        return;
    }

    // ---------- z = x @ w (A = x f32, in-kernel cvt; B = wt bf16 via gload_lds) ----------
    int bid = blockIdx.x;
    int wid = t >> 6, lane = t & 63;
    int cb = bid & 3, rb = bid >> 2;
    int rowBase = rb * 128, colBase = cb * 128;

    int ar = t >> 4, ac4 = t & 15;
    const float* aptr = x + (size_t)(rowBase + ar) * CC + ac4 * 4;
    int srow0 = t >> 3, ss = t & 7;

    f32x4 acc[4][4] = {};
    int wr = wid >> 1, wc = wid & 1;
    int fr = lane & 15, fq = lane >> 4;

    for (int kt = 0; kt < CC / 64; ++kt) {
#pragma unroll
        for (int i2 = 0; i2 < 8; ++i2) {
            float4 v = *(const float4*)(aptr + kt * 64 + (size_t)i2 * 16 * CC);
            int row = i2 * 16 + ar;
            ushort4 u2;
            u2.x = f2bf(v.x); u2.y = f2bf(v.y); u2.z = f2bf(v.z); u2.w = f2bf(v.w);
            *(ushort4*)((char*)As + row * 128 + ((ac4 * 8) ^ ((row & 7) << 4))) = u2;
        }
#pragma unroll
        for (int j = 0; j < 4; ++j) {
            int row = j * 32 + srow0;
            gload_lds16((const char*)(wt + (size_t)(colBase + row) * CC + kt * 64 +
                                      ((ss ^ (row & 7)) << 3)),
                        (char*)Bs + j * 4096 + wid * 1024);
        }
        __syncthreads();
#pragma unroll
        for (int ks = 0; ks < 2; ++ks) {
            short8 af[4], bfv[4];
#pragma unroll
            for (int m = 0; m < 4; ++m) {
                int row = wr * 64 + m * 16 + fr;
                af[m] = *(const short8*)((const char*)As + row * 128 +
                                         ((ks * 64 + fq * 16) ^ ((row & 7) << 4)));
            }
#pragma unroll
            for (int n = 0; n < 4; ++n) {
                int col = wc * 64 + n * 16 + fr;
                bfv[n] = *(const short8*)((const char*)Bs + col * 128 +
                                          ((ks * 64 + fq * 16) ^ ((col & 7) << 4)));
            }
#pragma unroll
            for (int m = 0; m < 4; ++m)
#pragma unroll
                for (int n = 0; n < 4; ++n)
                    acc[m][n] = __builtin_amdgcn_mfma_f32_16x16x32_bf16(af[m], bfv[n], acc[m][n], 0, 0, 0);
        }
        __syncthreads();
    }

#pragma unroll
    for (int m = 0; m < 4; ++m) {
#pragma unroll
        for (int j = 0; j < 4; ++j) {
            int gr = rowBase + wr * 64 + m * 16 + fq * 4 + j;
#pragma unroll
            for (int n = 0; n < 4; ++n) {
                int gc = colBase + wc * 64 + n * 16 + fr;
                z[(size_t)gr * CC + gc] = acc[m][n][j];
            }
        }
    }
}

// plain rowsum (fallback path)
__global__ __launch_bounds__(256) void k_rowsum(const float* __restrict__ adj,
                                                float* __restrict__ ds) {
    int row = blockIdx.x;
    const float4* p = (const float4*)(adj + (size_t)row * NN);
    float s = 0.f;
#pragma unroll
    for (int i = 0; i < 8; ++i) {
        float4 v = p[threadIdx.x + i * 256];
        s += (v.x + v.y) + (v.z + v.w);
    }
#pragma unroll
    for (int off = 32; off > 0; off >>= 1) s += __shfl_down(s, off, 64);
    __shared__ float partial[4];
    if ((threadIdx.x & 63) == 0) partial[threadIdx.x >> 6] = s;
    __syncthreads();
    if (threadIdx.x == 0) {
        float deg = ((partial[0] + partial[1]) + (partial[2] + partial[3])) + 1.0f;
        ds[row] = rsqrtf(deg);
    }
}

// ---------------- Kernel 2: out[c][r] = bf16( in[r][c] * (scale ? scale[r] : 1) ) ----------------
__global__ __launch_bounds__(256) void k_transpose(const float* __restrict__ in,
                                                   ushort_t* __restrict__ out,
                                                   const float* __restrict__ scale,
                                                   int R, int C) {
    __shared__ float tile[64][65];
    int r0 = blockIdx.x * 64, c0 = blockIdx.y * 64;
    int t = threadIdx.x;
    int cl = t & 63;
    int rl0 = t >> 6;
#pragma unroll
    for (int i = 0; i < 16; ++i) {
        int r = rl0 + i * 4;
        float v = in[(size_t)(r0 + r) * C + c0 + cl];
        float sc = scale ? scale[r0 + r] : 1.0f;
        tile[r][cl] = v * sc;
    }
    __syncthreads();
#pragma unroll
    for (int i = 0; i < 16; ++i) {
        int c = rl0 + i * 4;
        int r = cl;
        out[(size_t)(c0 + c) * R + r0 + r] = f2bf(tile[r][c]);
    }
}

// ---------------- small GEMM (fallback): out = [elu](A @ Bt), A bf16 ----------------
template <bool ELU>
__global__ __launch_bounds__(256, 2) void k_gemm2t(const ushort_t* __restrict__ A,
                                                   const ushort_t* __restrict__ Bt,
                                                   float* __restrict__ out) {
    __shared__ __align__(16) ushort_t As[128 * 64];
    __shared__ __align__(16) ushort_t Bs[128 * 64];

    int t = threadIdx.x;
    int wid = t >> 6, lane = t & 63;
    int bid = blockIdx.x;
    bid = (bid & 7) * 32 + (bid >> 3);
    int cb = bid & 3, rb = bid >> 2;
    int rowBase = rb * 128, colBase = cb * 128;

    int srow0 = t >> 3, ss = t & 7;

    f32x4 acc[4][4] = {};
    int wr = wid >> 1, wc = wid & 1;
    int fr = lane & 15, fq = lane >> 4;

    for (int kt = 0; kt < CC / 64; ++kt) {
#pragma unroll
        for (int j = 0; j < 4; ++j) {
            int row = j * 32 + srow0;
            gload_lds16((const char*)(A + (size_t)(rowBase + row) * CC + kt * 64 +
                                      ((ss ^ (row & 7)) << 3)),
                        (char*)As + j * 4096 + wid * 1024);
            gload_lds16((const char*)(Bt + (size_t)(colBase + row) * CC + kt * 64 +
                                      ((ss ^ (row & 7)) << 3)),
                        (char*)Bs + j * 4096 + wid * 1024);
        }
        __syncthreads();
#pragma unroll
        for (int ks = 0; ks < 2; ++ks) {
            short8 af[4], bfv[4];
#pragma unroll
            for (int m = 0; m < 4; ++m) {
                int row = wr * 64 + m * 16 + fr;
                af[m] = *(const short8*)((const char*)As + row * 128 +
                                         ((ks * 64 + fq * 16) ^ ((row & 7) << 4)));
            }
#pragma unroll
            for (int n = 0; n < 4; ++n) {
                int col = wc * 64 + n * 16 + fr;
                bfv[n] = *(const short8*)((const char*)Bs + col * 128 +
                                          ((ks * 64 + fq * 16) ^ ((col & 7) << 4)));
            }
#pragma unroll
            for (int m = 0; m < 4; ++m)
#pragma unroll
                for (int n = 0; n < 4; ++n)
                    acc[m][n] = __builtin_amdgcn_mfma_f32_16x16x32_bf16(af[m], bfv[n], acc[m][n], 0, 0, 0);
        }
        __syncthreads();
    }

#pragma unroll
    for (int m = 0; m < 4; ++m) {
#pragma unroll
        for (int j = 0; j < 4; ++j) {
            int gr = rowBase + wr * 64 + m * 16 + fq * 4 + j;
#pragma unroll
            for (int n = 0; n < 4; ++n) {
                int gc = colBase + wc * 64 + n * 16 + fr;
                float v = acc[m][n][j];
                out[(size_t)gr * CC + gc] = ELU ? (v > 0.f ? v : expm1f(v)) : v;
            }
        }
    }
}

// ---------------- Kernel 3 (primary): 128x128 tile, BK=32, 3-buf 2-deep prefetch, vmcnt(4)/iter,
//                  48 KB LDS -> 3 blocks/CU (12 waves/CU), 256 threads (4 waves, 2x2) ----------------
// adj16 bf16 [NN][NN]; yt2 bf16 [CC][NN]; part16 bf16 [4][NN][CC]
__global__ __launch_bounds__(256, 3) void k_gemm1g(const ushort_t* __restrict__ adj16,
                                                   const ushort_t* __restrict__ yt2,
                                                   ushort_t* __restrict__ part16) {
    __shared__ __align__(16) ushort_t Al[3][128 * 32];   // 3 x 8 KB
    __shared__ __align__(16) ushort_t Bl[3][128 * 32];   // 3 x 8 KB -> 48 KB total

    int t = threadIdx.x;
    int wid = t >> 6, lane = t & 63;
    int fr = lane & 15, fq = lane >> 4;

    // grid 1024 = xcd(8) x slot(128); slot -> cb(4) x u; u = (slot>>2) + 32*xcd in [0,256) bijective
    int gid = blockIdx.x;
    int xcd = gid & 7, slot = gid >> 3;
    int cb = slot & 3;
    int u = (slot >> 2) + 32 * xcd;
    int rb = u & 63, ks = u >> 6;
    int rowBase = rb * 128, colBase = cb * 128;
    int kt0 = ks * 64;                          // K32-tile units; chunk = 64 tiles (K=2048)

    int wr = wid >> 1, wc = wid & 1;            // 2 x 2 waves; wave tile 64 x 64

    // staging: thread t -> row (t>>2) in [0,64), 16B chunk (t&3); two loads cover rows 0-63 / 64-127
    // swizzle: chunk ^= (row>>1)&3  (row+64 keeps same xor: 64>>1=32 ≡ 0 mod 4)
    int srow = t >> 2;
    int sw = ((t & 3) ^ ((srow >> 1) & 3)) << 3;
    const ushort_t* aBase = adj16 + (size_t)(rowBase + srow) * NN + sw;
    const ushort_t* bBase = yt2 + (size_t)(colBase + srow) * NN + sw;

    auto stage = [&](int buf, int tile) {       // 4 loads: A rows 0-63, A rows 64-127, B rows 0-63, B rows 64-127
        gload_lds16(aBase + (size_t)tile * 32, (char*)Al[buf] + wid * 1024);
        gload_lds16(aBase + (size_t)64 * NN + (size_t)tile * 32, (char*)Al[buf] + 4096 + wid * 1024);
        gload_lds16(bBase + (size_t)tile * 32, (char*)Bl[buf] + wid * 1024);
        gload_lds16(bBase + (size_t)64 * NN + (size_t)tile * 32, (char*)Bl[buf] + 4096 + wid * 1024);
    };

    f32x4 acc[4][4] = {};
    int sws = (fq ^ ((fr >> 1) & 3)) << 4;      // swizzled 16B-chunk byte offset for frag reads

    // prologue: tiles 0,1 -> bufs 0,1 (8 loads); vmcnt(4) confirms tile 0
    stage(0, kt0 + 0);
    stage(1, kt0 + 1);
    asm volatile("s_waitcnt vmcnt(4)" ::: "memory");
    __builtin_amdgcn_sched_barrier(0);
    __builtin_amdgcn_s_barrier();

    int cur = 0, nxt = 2;                       // nxt = (i+2)%3
    for (int i = 0; i < 64; ++i) {
        const char* Ab = (const char*)Al[cur] + wr * 4096;   // wr*64 rows * 64B
        const char* Bb = (const char*)Bl[cur] + wc * 4096;   // wc*64 cols * 64B

        short8 af[4], bfv[4];
#pragma unroll
        for (int m = 0; m < 4; ++m)
            af[m] = *(const short8*)(Ab + (m * 16 + fr) * 64 + sws);
#pragma unroll
        for (int n = 0; n < 4; ++n)
            bfv[n] = *(const short8*)(Bb + (n * 16 + fr) * 64 + sws);

        stage(nxt, kt0 + ((i + 2) & 63));       // wrap -> dead re-stage on last 2 iters (safe)

        __builtin_amdgcn_s_setprio(1);
#pragma unroll
        for (int m = 0; m < 4; ++m)
#pragma unroll
            for (int n = 0; n < 4; ++n)
                acc[m][n] = __builtin_amdgcn_mfma_f32_16x16x32_bf16(af[m], bfv[n], acc[m][n], 0, 0, 0);
        __builtin_amdgcn_s_setprio(0);

        asm volatile("s_waitcnt vmcnt(4)" ::: "memory");   // tile i+1 confirmed; i+2 in flight
        __builtin_amdgcn_sched_barrier(0);
        __builtin_amdgcn_s_barrier();

        cur = cur == 2 ? 0 : cur + 1;
        nxt = nxt == 2 ? 0 : nxt + 1;
    }

    // epilogue: bf16 partials
#pragma unroll
    for (int m = 0; m < 4; ++m) {
#pragma unroll
        for (int jj = 0; jj < 4; ++jj) {
            int gr = rowBase + wr * 64 + m * 16 + fq * 4 + jj;
            ushort_t* dst = part16 + ((size_t)ks * NN + gr) * CC + colBase;
#pragma unroll
            for (int n = 0; n < 4; ++n)
                dst[wc * 64 + n * 16 + fr] = f2bf(acc[m][n][jj]);
        }
    }
}

// ---------------- finish2: out = elu( ds*(sum partials) + ds^2 * z ) ----------------
__global__ __launch_bounds__(256) void k_finish2(const ushort_t* __restrict__ part16,
                                                 const float* __restrict__ ds,
                                                 const float* __restrict__ z,
                                                 float* __restrict__ out) {
    size_t i = (size_t)blockIdx.x * 256 + threadIdx.x;
    const size_t stride = (size_t)NN * CC / 4;
    float s0 = 0.f, s1 = 0.f, s2 = 0.f, s3 = 0.f;
#pragma unroll
    for (int k = 0; k < 4; ++k) {
        ushort4 p = ((const ushort4*)part16)[i + k * stride];
        s0 += bf2f(p.x); s1 += bf2f(p.y); s2 += bf2f(p.z); s3 += bf2f(p.w);
    }
    int row = (int)(i >> 7);
    float d = ds[row];
    float d2 = d * d;
    f32x4 zv = ((const f32x4*)z)[i];
    f32x4 o;
    float v;
    v = d * s0 + d2 * zv[0]; o[0] = v > 0.f ? v : expm1f(v);
    v = d * s1 + d2 * zv[1]; o[1] = v > 0.f ? v : expm1f(v);
    v = d * s2 + d2 * zv[2]; o[2] = v > 0.f ? v : expm1f(v);
    v = d * s3 + d2 * zv[3]; o[3] = v > 0.f ? v : expm1f(v);
    ((f32x4*)out)[i] = o;
}

// ---------------- fallback full-K GEMM1 (f32 A in-kernel convert) + old epilogue ----------------
__global__ __launch_bounds__(256, 4) void k_gemm1_fb(const float* __restrict__ adj,
                                                     const ushort_t* __restrict__ yt,
                                                     const float* __restrict__ ds,
                                                     const float* __restrict__ x,
                                                     ushort_t* __restrict__ mm1) {
    __shared__ __align__(16) ushort_t As[128 * 64];
    __shared__ __align__(16) ushort_t Bs[128 * 64];

    int t = threadIdx.x;
    int wid = t >> 6, lane = t & 63;
    int bid = blockIdx.x;
    bid = (bid & 7) * 32 + (bid >> 3);
    int colBase = (bid & 3) * 128;
    int rowBase = (bid >> 2) * 128;

    int ar = t >> 4;
    int ac4 = t & 15;
    const float* aptr = adj + (size_t)(rowBase + ar) * NN + ac4 * 4;
    int brow0 = t >> 3;
    int bs = t & 7;
    float4 areg[8];

    auto loadA = [&](int kt) {
        const float* p = aptr + kt * 64;
#pragma unroll
        for (int i = 0; i < 8; ++i)
            areg[i] = *(const float4*)(p + (size_t)i * 16 * NN);
    };
    auto writeA = [&]() {
#pragma unroll
        for (int i = 0; i < 8; ++i) {
            int row = i * 16 + ar;
            ushort4 u;
            u.x = f2bf(areg[i].x); u.y = f2bf(areg[i].y);
            u.z = f2bf(areg[i].z); u.w = f2bf(areg[i].w);
            *(ushort4*)((char*)As + row * 128 + ((ac4 * 8) ^ ((row & 7) << 4))) = u;
        }
    };

    f32x4 acc[4][4] = {};
    int wr = wid >> 1, wc = wid & 1;
    int fr = lane & 15, fq = lane >> 4;

    loadA(0);
    for (int kt = 0; kt < NN / 64; ++kt) {
        writeA();
#pragma unroll
        for (int j = 0; j < 4; ++j) {
            int row = j * 32 + brow0;
            gload_lds16((const char*)(yt + (size_t)(colBase + row) * NN + kt * 64 +
                                      ((bs ^ (row & 7)) << 3)),
                        (char*)Bs + j * 4096 + wid * 1024);
        }
        __syncthreads();
        if (kt + 1 < NN / 64) loadA(kt + 1);
#pragma unroll
        for (int ks2 = 0; ks2 < 2; ++ks2) {
            short8 af[4], bfv[4];
#pragma unroll
            for (int m = 0; m < 4; ++m) {
                int row = wr * 64 + m * 16 + fr;
                af[m] = *(const short8*)((const char*)As + row * 128 +
                                         ((ks2 * 64 + fq * 16) ^ ((row & 7) << 4)));
            }
#pragma unroll
            for (int n = 0; n < 4; ++n) {
                int col = wc * 64 + n * 16 + fr;
                bfv[n] = *(const short8*)((const char*)Bs + col * 128 +
                                          ((ks2 * 64 + fq * 16) ^ ((col & 7) << 4)));
            }
#pragma unroll
            for (int m = 0; m < 4; ++m)
#pragma unroll
                for (int n = 0; n < 4; ++n)
                    acc[m][n] = __builtin_amdgcn_mfma_f32_16x16x32_bf16(af[m], bfv[n], acc[m][n], 0, 0, 0);
        }
        __syncthreads();
    }

#pragma unroll
    for (int m = 0; m < 4; ++m) {
#pragma unroll
        for (int j = 0; j < 4; ++j) {
            int gr = rowBase + wr * 64 + m * 16 + fq * 4 + j;
            float dsr = ds[gr];
#pragma unroll
            for (int n = 0; n < 4; ++n) {
                int gc = colBase + wc * 64 + n * 16 + fr;
                float v = dsr * (acc[m][n][j] + dsr * x[(size_t)gr * CC + gc]);
                mm1[(size_t)gr * CC + gc] = f2bf(v);
            }
        }
    }
}

extern "C" void kernel_launch(void* const* d_in, const int* in_sizes, int n_in,
                              void* d_out, int out_size, void* d_ws, size_t ws_size,
                              hipStream_t stream) {
    const float* x   = (const float*)d_in[0];   // [8192][512]
    const float* adj = (const float*)d_in[1];   // [8192][8192]
    const float* w   = (const float*)d_in[2];   // [512][512]
    float* out = (float*)d_out;                 // [8192][512]

    char* ws = (char*)d_ws;
    size_t off = 0;
    float*    ds  = (float*)(ws + off);  off += 32u << 10;               // 32 KB
    ushort_t* yt  = (ushort_t*)(ws + off);  off += 8u << 20;             // 8 MB
    ushort_t* wt  = (ushort_t*)(ws + off);  off += 512u << 10;           // 512 KB
    ushort_t* xb  = (ushort_t*)(ws + off);  off += 8u << 20;             // 8 MB (fallback mm1)
    float*    z   = (float*)(ws + off);  off += 16u << 20;               // 16 MB
    ushort_t* part16 = (ushort_t*)(ws + off);  off += 32u << 20;         // 32 MB
    ushort_t* adj16  = (ushort_t*)(ws + off);                             // 128 MB
    const size_t adjBytes = (size_t)NN * NN * 2;

    if (ws_size >= off + adjBytes) {
        k_transpose<<<dim3(CC / 64, CC / 64), 256, 0, stream>>>(w, wt, nullptr, CC, CC);
        k_pre<<<NN + 256, 256, 0, stream>>>(x, adj, wt, ds, adj16, z);   // rowsum+cvt || z=x@w
        k_transpose<<<dim3(NN / 64, CC / 64), 256, 0, stream>>>(z, yt, ds, NN, CC);
        k_gemm1g<<<1024, 256, 0, stream>>>(adj16, yt, part16);
        k_finish2<<<NN * CC / 4 / 256, 256, 0, stream>>>(part16, ds, z, out);
    } else {
        ushort_t* mm1 = xb;
        k_rowsum<<<NN, 256, 0, stream>>>(adj, ds);
        k_transpose<<<dim3(NN / 64, CC / 64), 256, 0, stream>>>(x, yt, ds, NN, CC);
        k_transpose<<<dim3(CC / 64, CC / 64), 256, 0, stream>>>(w, wt, nullptr, CC, CC);
        k_gemm1_fb<<<256, 256, 0, stream>>>(adj, yt, ds, x, mm1);
        k_gemm2t<true><<<256, 256, 0, stream>>>(mm1, wt, out);
    }
}

// Round 14
// 195.480 us; speedup vs baseline: 1.1000x; 1.1000x over previous
//
#include <hip/hip_runtime.h>

#define NN 8192
#define CC 512

typedef __attribute__((ext_vector_type(8))) short short8;
typedef __attribute__((ext_vector_type(4))) float f32x4;
typedef unsigned short ushort_t;

__device__ __forceinline__ unsigned short f2bf(float f) {
    unsigned int u = __float_as_uint(f);
    u += 0x7FFF + ((u >> 16) & 1);
    return (unsigned short)(u >> 16);
}
__device__ __forceinline__ float bf2f(unsigned short u) {
    return __uint_as_float(((unsigned int)u) << 16);
}

__device__ __forceinline__ void gload_lds16(const void* g, void* l) {
    __builtin_amdgcn_global_load_lds((const __attribute__((address_space(1))) unsigned int*)g,
                                     (__attribute__((address_space(3))) unsigned int*)l,
                                     16, 0, 0);
}

// ---------------- fused pre-kernel: blocks 0..255 -> z = x@w ; blocks 256..8447 -> rowsum+cvt ----------------
__global__ __launch_bounds__(256) void k_pre(const float* __restrict__ x,
                                             const float* __restrict__ adj,
                                             const ushort_t* __restrict__ wt,
                                             float* __restrict__ ds,
                                             ushort_t* __restrict__ adj16,
                                             float* __restrict__ z) {
    __shared__ __align__(16) ushort_t As[128 * 64];
    __shared__ __align__(16) ushort_t Bs[128 * 64];
    __shared__ float partial[4];

    int t = threadIdx.x;
    if (blockIdx.x >= 256) {
        // ---------- rowsum + bf16 convert ----------
        int row = blockIdx.x - 256;
        const float4* p = (const float4*)(adj + (size_t)row * NN);
        ushort4* q = (ushort4*)(adj16 + (size_t)row * NN);
        float s = 0.f;
#pragma unroll
        for (int i = 0; i < 8; ++i) {
            float4 v = p[t + i * 256];
            s += (v.x + v.y) + (v.z + v.w);
            ushort4 u;
            u.x = f2bf(v.x); u.y = f2bf(v.y); u.z = f2bf(v.z); u.w = f2bf(v.w);
            q[t + i * 256] = u;
        }
#pragma unroll
        for (int off = 32; off > 0; off >>= 1) s += __shfl_down(s, off, 64);
        if ((t & 63) == 0) partial[t >> 6] = s;
        __syncthreads();
        if (t == 0) {
            float deg = ((partial[0] + partial[1]) + (partial[2] + partial[3])) + 1.0f;
            ds[row] = rsqrtf(deg);
        }
        return;
    }

    // ---------- z = x @ w (A = x f32, in-kernel cvt; B = wt bf16 via gload_lds) ----------
    int bid = blockIdx.x;
    int wid = t >> 6, lane = t & 63;
    int cb = bid & 3, rb = bid >> 2;
    int rowBase = rb * 128, colBase = cb * 128;

    int ar = t >> 4, ac4 = t & 15;
    const float* aptr = x + (size_t)(rowBase + ar) * CC + ac4 * 4;
    int srow0 = t >> 3, ss = t & 7;

    f32x4 acc[4][4] = {};
    int wr = wid >> 1, wc = wid & 1;
    int fr = lane & 15, fq = lane >> 4;

    for (int kt = 0; kt < CC / 64; ++kt) {
#pragma unroll
        for (int i2 = 0; i2 < 8; ++i2) {
            float4 v = *(const float4*)(aptr + kt * 64 + (size_t)i2 * 16 * CC);
            int row = i2 * 16 + ar;
            ushort4 u2;
            u2.x = f2bf(v.x); u2.y = f2bf(v.y); u2.z = f2bf(v.z); u2.w = f2bf(v.w);
            *(ushort4*)((char*)As + row * 128 + ((ac4 * 8) ^ ((row & 7) << 4))) = u2;
        }
#pragma unroll
        for (int j = 0; j < 4; ++j) {
            int row = j * 32 + srow0;
            gload_lds16((const char*)(wt + (size_t)(colBase + row) * CC + kt * 64 +
                                      ((ss ^ (row & 7)) << 3)),
                        (char*)Bs + j * 4096 + wid * 1024);
        }
        __syncthreads();
#pragma unroll
        for (int ks = 0; ks < 2; ++ks) {
            short8 af[4], bfv[4];
#pragma unroll
            for (int m = 0; m < 4; ++m) {
                int row = wr * 64 + m * 16 + fr;
                af[m] = *(const short8*)((const char*)As + row * 128 +
                                         ((ks * 64 + fq * 16) ^ ((row & 7) << 4)));
            }
#pragma unroll
            for (int n = 0; n < 4; ++n) {
                int col = wc * 64 + n * 16 + fr;
                bfv[n] = *(const short8*)((const char*)Bs + col * 128 +
                                          ((ks * 64 + fq * 16) ^ ((col & 7) << 4)));
            }
#pragma unroll
            for (int m = 0; m < 4; ++m)
#pragma unroll
                for (int n = 0; n < 4; ++n)
                    acc[m][n] = __builtin_amdgcn_mfma_f32_16x16x32_bf16(af[m], bfv[n], acc[m][n], 0, 0, 0);
        }
        __syncthreads();
    }

#pragma unroll
    for (int m = 0; m < 4; ++m) {
#pragma unroll
        for (int j = 0; j < 4; ++j) {
            int gr = rowBase + wr * 64 + m * 16 + fq * 4 + j;
#pragma unroll
            for (int n = 0; n < 4; ++n) {
                int gc = colBase + wc * 64 + n * 16 + fr;
                z[(size_t)gr * CC + gc] = acc[m][n][j];
            }
        }
    }
}

// plain rowsum (fallback path)
__global__ __launch_bounds__(256) void k_rowsum(const float* __restrict__ adj,
                                                float* __restrict__ ds) {
    int row = blockIdx.x;
    const float4* p = (const float4*)(adj + (size_t)row * NN);
    float s = 0.f;
#pragma unroll
    for (int i = 0; i < 8; ++i) {
        float4 v = p[threadIdx.x + i * 256];
        s += (v.x + v.y) + (v.z + v.w);
    }
#pragma unroll
    for (int off = 32; off > 0; off >>= 1) s += __shfl_down(s, off, 64);
    __shared__ float partial[4];
    if ((threadIdx.x & 63) == 0) partial[threadIdx.x >> 6] = s;
    __syncthreads();
    if (threadIdx.x == 0) {
        float deg = ((partial[0] + partial[1]) + (partial[2] + partial[3])) + 1.0f;
        ds[row] = rsqrtf(deg);
    }
}

// ---------------- Kernel 2: out[c][r] = bf16( in[r][c] * (scale ? scale[r] : 1) ) ----------------
__global__ __launch_bounds__(256) void k_transpose(const float* __restrict__ in,
                                                   ushort_t* __restrict__ out,
                                                   const float* __restrict__ scale,
                                                   int R, int C) {
    __shared__ float tile[64][65];
    int r0 = blockIdx.x * 64, c0 = blockIdx.y * 64;
    int t = threadIdx.x;
    int cl = t & 63;
    int rl0 = t >> 6;
#pragma unroll
    for (int i = 0; i < 16; ++i) {
        int r = rl0 + i * 4;
        float v = in[(size_t)(r0 + r) * C + c0 + cl];
        float sc = scale ? scale[r0 + r] : 1.0f;
        tile[r][cl] = v * sc;
    }
    __syncthreads();
#pragma unroll
    for (int i = 0; i < 16; ++i) {
        int c = rl0 + i * 4;
        int r = cl;
        out[(size_t)(c0 + c) * R + r0 + r] = f2bf(tile[r][c]);
    }
}

// ---------------- small GEMM (fallback): out = [elu](A @ Bt), A bf16 ----------------
template <bool ELU>
__global__ __launch_bounds__(256, 2) void k_gemm2t(const ushort_t* __restrict__ A,
                                                   const ushort_t* __restrict__ Bt,
                                                   float* __restrict__ out) {
    __shared__ __align__(16) ushort_t As[128 * 64];
    __shared__ __align__(16) ushort_t Bs[128 * 64];

    int t = threadIdx.x;
    int wid = t >> 6, lane = t & 63;
    int bid = blockIdx.x;
    bid = (bid & 7) * 32 + (bid >> 3);
    int cb = bid & 3, rb = bid >> 2;
    int rowBase = rb * 128, colBase = cb * 128;

    int srow0 = t >> 3, ss = t & 7;

    f32x4 acc[4][4] = {};
    int wr = wid >> 1, wc = wid & 1;
    int fr = lane & 15, fq = lane >> 4;

    for (int kt = 0; kt < CC / 64; ++kt) {
#pragma unroll
        for (int j = 0; j < 4; ++j) {
            int row = j * 32 + srow0;
            gload_lds16((const char*)(A + (size_t)(rowBase + row) * CC + kt * 64 +
                                      ((ss ^ (row & 7)) << 3)),
                        (char*)As + j * 4096 + wid * 1024);
            gload_lds16((const char*)(Bt + (size_t)(colBase + row) * CC + kt * 64 +
                                      ((ss ^ (row & 7)) << 3)),
                        (char*)Bs + j * 4096 + wid * 1024);
        }
        __syncthreads();
#pragma unroll
        for (int ks = 0; ks < 2; ++ks) {
            short8 af[4], bfv[4];
#pragma unroll
            for (int m = 0; m < 4; ++m) {
                int row = wr * 64 + m * 16 + fr;
                af[m] = *(const short8*)((const char*)As + row * 128 +
                                         ((ks * 64 + fq * 16) ^ ((row & 7) << 4)));
            }
#pragma unroll
            for (int n = 0; n < 4; ++n) {
                int col = wc * 64 + n * 16 + fr;
                bfv[n] = *(const short8*)((const char*)Bs + col * 128 +
                                          ((ks * 64 + fq * 16) ^ ((col & 7) << 4)));
            }
#pragma unroll
            for (int m = 0; m < 4; ++m)
#pragma unroll
                for (int n = 0; n < 4; ++n)
                    acc[m][n] = __builtin_amdgcn_mfma_f32_16x16x32_bf16(af[m], bfv[n], acc[m][n], 0, 0, 0);
        }
        __syncthreads();
    }

#pragma unroll
    for (int m = 0; m < 4; ++m) {
#pragma unroll
        for (int j = 0; j < 4; ++j) {
            int gr = rowBase + wr * 64 + m * 16 + fq * 4 + j;
#pragma unroll
            for (int n = 0; n < 4; ++n) {
                int gc = colBase + wc * 64 + n * 16 + fr;
                float v = acc[m][n][j];
                out[(size_t)gr * CC + gc] = ELU ? (v > 0.f ? v : expm1f(v)) : v;
            }
        }
    }
}

// ---------------- Kernel 3 (primary): 256x128 tile, BK=32, 3-buf 2-deep prefetch, vmcnt(3)/iter,
//                  2 blocks/CU (LDS 72KB, acc 64 VGPR) ----------------
__global__ __launch_bounds__(512, 4) void k_gemm1e(const ushort_t* __restrict__ adj16,
                                                   const ushort_t* __restrict__ yt2,
                                                   ushort_t* __restrict__ part16) {
    __shared__ __align__(16) ushort_t Al[3][256 * 32];   // 3 x 16 KB
    __shared__ __align__(16) ushort_t Bl[3][128 * 32];   // 3 x  8 KB  -> 72 KB total

    int t = threadIdx.x;
    int wid = t >> 6, lane = t & 63;
    int fr = lane & 15, fq = lane >> 4;

    // grid 512 = xcd(8) x slot(64); slot -> cb(4) x v; v = (slot>>2) + 16*xcd in [0,128) bijective
    int gid = blockIdx.x;
    int xcd = gid & 7, slot = gid >> 3;
    int cb = slot & 3;
    int v = (slot >> 2) + 16 * xcd;
    int rb = v & 31, ks = v >> 5;
    int rowBase = rb * 256, colBase = cb * 128;
    int kt0 = ks * 64;                          // K32-tile units; chunk = 64 tiles (K=2048)

    int wr = wid >> 1, wc = wid & 1;            // 4 x 2 waves; wave tile 64 x 64
    int srow = t >> 2;
    int sw = ((t & 3) ^ ((srow >> 1) & 3)) << 3;
    const ushort_t* aBase = adj16 + (size_t)(rowBase + srow) * NN + sw;
    const ushort_t* bBase = yt2 + (size_t)(colBase + srow) * NN + sw;

    auto stage = [&](int buf, int tile) {       // 3 loads: A rows 0-127, A rows 128-255, B rows 0-127
        gload_lds16(aBase + (size_t)tile * 32, (char*)Al[buf] + wid * 1024);
        gload_lds16(aBase + (size_t)128 * NN + (size_t)tile * 32, (char*)Al[buf] + 8192 + wid * 1024);
        gload_lds16(bBase + (size_t)tile * 32, (char*)Bl[buf] + wid * 1024);
    };

    f32x4 acc[4][4] = {};
    int sws = (fq ^ ((fr >> 1) & 3)) << 4;      // swizzled 16B-chunk byte offset for frag reads

    // prologue: tiles 0,1 -> bufs 0,1 (6 loads); vmcnt(3) confirms tile 0
    stage(0, kt0 + 0);
    stage(1, kt0 + 1);
    asm volatile("s_waitcnt vmcnt(3)" ::: "memory");
    __builtin_amdgcn_sched_barrier(0);
    __builtin_amdgcn_s_barrier();

    int cur = 0, nxt = 2;                       // nxt = (i+2)%3
    for (int i = 0; i < 64; ++i) {
        const char* Ab = (const char*)Al[cur] + wr * 4096;   // wr*64 rows * 64B
        const char* Bb = (const char*)Bl[cur] + wc * 4096;   // wc*64 cols * 64B

        short8 af[4], bfv[4];
#pragma unroll
        for (int m = 0; m < 4; ++m)
            af[m] = *(const short8*)(Ab + (m * 16 + fr) * 64 + sws);
#pragma unroll
        for (int n = 0; n < 4; ++n)
            bfv[n] = *(const short8*)(Bb + (n * 16 + fr) * 64 + sws);

        stage(nxt, kt0 + ((i + 2) & 63));       // wrap -> dead re-stage on last 2 iters (safe)

        __builtin_amdgcn_s_setprio(1);
#pragma unroll
        for (int m = 0; m < 4; ++m)
#pragma unroll
            for (int n = 0; n < 4; ++n)
                acc[m][n] = __builtin_amdgcn_mfma_f32_16x16x32_bf16(af[m], bfv[n], acc[m][n], 0, 0, 0);
        __builtin_amdgcn_s_setprio(0);

        asm volatile("s_waitcnt vmcnt(3)" ::: "memory");   // tile i+1 confirmed; i+2 in flight
        __builtin_amdgcn_sched_barrier(0);
        __builtin_amdgcn_s_barrier();

        cur = cur == 2 ? 0 : cur + 1;
        nxt = nxt == 2 ? 0 : nxt + 1;
    }

    // epilogue: bf16 partials
#pragma unroll
    for (int m = 0; m < 4; ++m) {
#pragma unroll
        for (int jj = 0; jj < 4; ++jj) {
            int gr = rowBase + wr * 64 + m * 16 + fq * 4 + jj;
            ushort_t* dst = part16 + ((size_t)ks * NN + gr) * CC + colBase;
#pragma unroll
            for (int n = 0; n < 4; ++n)
                dst[wc * 64 + n * 16 + fr] = f2bf(acc[m][n][jj]);
        }
    }
}

// ---------------- finish2: out = elu( ds*(sum partials) + ds^2 * z ) ----------------
__global__ __launch_bounds__(256) void k_finish2(const ushort_t* __restrict__ part16,
                                                 const float* __restrict__ ds,
                                                 const float* __restrict__ z,
                                                 float* __restrict__ out) {
    size_t i = (size_t)blockIdx.x * 256 + threadIdx.x;
    const size_t stride = (size_t)NN * CC / 4;
    float s0 = 0.f, s1 = 0.f, s2 = 0.f, s3 = 0.f;
#pragma unroll
    for (int k = 0; k < 4; ++k) {
        ushort4 p = ((const ushort4*)part16)[i + k * stride];
        s0 += bf2f(p.x); s1 += bf2f(p.y); s2 += bf2f(p.z); s3 += bf2f(p.w);
    }
    int row = (int)(i >> 7);
    float d = ds[row];
    float d2 = d * d;
    f32x4 zv = ((const f32x4*)z)[i];
    f32x4 o;
    float v;
    v = d * s0 + d2 * zv[0]; o[0] = v > 0.f ? v : expm1f(v);
    v = d * s1 + d2 * zv[1]; o[1] = v > 0.f ? v : expm1f(v);
    v = d * s2 + d2 * zv[2]; o[2] = v > 0.f ? v : expm1f(v);
    v = d * s3 + d2 * zv[3]; o[3] = v > 0.f ? v : expm1f(v);
    ((f32x4*)out)[i] = o;
}

// ---------------- fallback full-K GEMM1 (f32 A in-kernel convert) + old epilogue ----------------
__global__ __launch_bounds__(256, 4) void k_gemm1_fb(const float* __restrict__ adj,
                                                     const ushort_t* __restrict__ yt,
                                                     const float* __restrict__ ds,
                                                     const float* __restrict__ x,
                                                     ushort_t* __restrict__ mm1) {
    __shared__ __align__(16) ushort_t As[128 * 64];
    __shared__ __align__(16) ushort_t Bs[128 * 64];

    int t = threadIdx.x;
    int wid = t >> 6, lane = t & 63;
    int bid = blockIdx.x;
    bid = (bid & 7) * 32 + (bid >> 3);
    int colBase = (bid & 3) * 128;
    int rowBase = (bid >> 2) * 128;

    int ar = t >> 4;
    int ac4 = t & 15;
    const float* aptr = adj + (size_t)(rowBase + ar) * NN + ac4 * 4;
    int brow0 = t >> 3;
    int bs = t & 7;
    float4 areg[8];

    auto loadA = [&](int kt) {
        const float* p = aptr + kt * 64;
#pragma unroll
        for (int i = 0; i < 8; ++i)
            areg[i] = *(const float4*)(p + (size_t)i * 16 * NN);
    };
    auto writeA = [&]() {
#pragma unroll
        for (int i = 0; i < 8; ++i) {
            int row = i * 16 + ar;
            ushort4 u;
            u.x = f2bf(areg[i].x); u.y = f2bf(areg[i].y);
            u.z = f2bf(areg[i].z); u.w = f2bf(areg[i].w);
            *(ushort4*)((char*)As + row * 128 + ((ac4 * 8) ^ ((row & 7) << 4))) = u;
        }
    };

    f32x4 acc[4][4] = {};
    int wr = wid >> 1, wc = wid & 1;
    int fr = lane & 15, fq = lane >> 4;

    loadA(0);
    for (int kt = 0; kt < NN / 64; ++kt) {
        writeA();
#pragma unroll
        for (int j = 0; j < 4; ++j) {
            int row = j * 32 + brow0;
            gload_lds16((const char*)(yt + (size_t)(colBase + row) * NN + kt * 64 +
                                      ((bs ^ (row & 7)) << 3)),
                        (char*)Bs + j * 4096 + wid * 1024);
        }
        __syncthreads();
        if (kt + 1 < NN / 64) loadA(kt + 1);
#pragma unroll
        for (int ks2 = 0; ks2 < 2; ++ks2) {
            short8 af[4], bfv[4];
#pragma unroll
            for (int m = 0; m < 4; ++m) {
                int row = wr * 64 + m * 16 + fr;
                af[m] = *(const short8*)((const char*)As + row * 128 +
                                         ((ks2 * 64 + fq * 16) ^ ((row & 7) << 4)));
            }
#pragma unroll
            for (int n = 0; n < 4; ++n) {
                int col = wc * 64 + n * 16 + fr;
                bfv[n] = *(const short8*)((const char*)Bs + col * 128 +
                                          ((ks2 * 64 + fq * 16) ^ ((col & 7) << 4)));
            }
#pragma unroll
            for (int m = 0; m < 4; ++m)
#pragma unroll
                for (int n = 0; n < 4; ++n)
                    acc[m][n] = __builtin_amdgcn_mfma_f32_16x16x32_bf16(af[m], bfv[n], acc[m][n], 0, 0, 0);
        }
        __syncthreads();
    }

#pragma unroll
    for (int m = 0; m < 4; ++m) {
#pragma unroll
        for (int j = 0; j < 4; ++j) {
            int gr = rowBase + wr * 64 + m * 16 + fq * 4 + j;
            float dsr = ds[gr];
#pragma unroll
            for (int n = 0; n < 4; ++n) {
                int gc = colBase + wc * 64 + n * 16 + fr;
                float v = dsr * (acc[m][n][j] + dsr * x[(size_t)gr * CC + gc]);
                mm1[(size_t)gr * CC + gc] = f2bf(v);
            }
        }
    }
}

extern "C" void kernel_launch(void* const* d_in, const int* in_sizes, int n_in,
                              void* d_out, int out_size, void* d_ws, size_t ws_size,
                              hipStream_t stream) {
    const float* x   = (const float*)d_in[0];   // [8192][512]
    const float* adj = (const float*)d_in[1];   // [8192][8192]
    const float* w   = (const float*)d_in[2];   // [512][512]
    float* out = (float*)d_out;                 // [8192][512]

    char* ws = (char*)d_ws;
    size_t off = 0;
    float*    ds  = (float*)(ws + off);  off += 32u << 10;               // 32 KB
    ushort_t* yt  = (ushort_t*)(ws + off);  off += 8u << 20;             // 8 MB
    ushort_t* wt  = (ushort_t*)(ws + off);  off += 512u << 10;           // 512 KB
    ushort_t* xb  = (ushort_t*)(ws + off);  off += 8u << 20;             // 8 MB (fallback mm1)
    float*    z   = (float*)(ws + off);  off += 16u << 20;               // 16 MB
    ushort_t* part16 = (ushort_t*)(ws + off);  off += 32u << 20;         // 32 MB
    ushort_t* adj16  = (ushort_t*)(ws + off);                             // 128 MB
    const size_t adjBytes = (size_t)NN * NN * 2;

    if (ws_size >= off + adjBytes) {
        k_transpose<<<dim3(CC / 64, CC / 64), 256, 0, stream>>>(w, wt, nullptr, CC, CC);
        k_pre<<<NN + 256, 256, 0, stream>>>(x, adj, wt, ds, adj16, z);   // rowsum+cvt || z=x@w
        k_transpose<<<dim3(NN / 64, CC / 64), 256, 0, stream>>>(z, yt, ds, NN, CC);
        k_gemm1e<<<512, 512, 0, stream>>>(adj16, yt, part16);
        k_finish2<<<NN * CC / 4 / 256, 256, 0, stream>>>(part16, ds, z, out);
    } else {
        ushort_t* mm1 = xb;
        k_rowsum<<<NN, 256, 0, stream>>>(adj, ds);
        k_transpose<<<dim3(NN / 64, CC / 64), 256, 0, stream>>>(x, yt, ds, NN, CC);
        k_transpose<<<dim3(CC / 64, CC / 64), 256, 0, stream>>>(w, wt, nullptr, CC, CC);
        k_gemm1_fb<<<256, 256, 0, stream>>>(adj, yt, ds, x, mm1);
        k_gemm2t<true><<<256, 256, 0, stream>>>(mm1, wt, out);
    }
}